// Round 5
// baseline (488.373 us; speedup 1.0000x reference)
//
#include <hip/hip_runtime.h>
#include <math.h>

constexpr int B_ = 2, S_ = 2048, D_ = 2048, NH_ = 16, NKV_ = 4, HD_ = 128;
constexpr int EQKV_ = (NH_ + 2 * NKV_) * HD_;   // 3072
constexpr int M_ = B_ * S_;                     // 4096
constexpr float EPS_ = 1e-6f;
constexpr float QSCALE_ = 0.08838834764831845f; // 1/sqrt(HD)

typedef __attribute__((ext_vector_type(8))) short bf16x8;
typedef __attribute__((ext_vector_type(4))) float f32x4;
typedef __attribute__((address_space(1))) unsigned int gu32;
typedef __attribute__((address_space(3))) unsigned int lu32;

__device__ inline ushort f2bf(float f) {   // RNE fp32->bf16 (finite inputs)
    unsigned u = __float_as_uint(f);
    return (ushort)((u + 0x7FFF + ((u >> 16) & 1)) >> 16);
}

// ---------------- pack: fp32 -> bf16, float4 per thread --------------------
__global__ __launch_bounds__(256) void pack_bf16(
    const float* __restrict__ in, ushort* __restrict__ out, int n4)
{
    int i = blockIdx.x * 256 + threadIdx.x;
    if (i >= n4) return;
    float4 f = ((const float4*)in)[i];
    ushort4 u;
    u.x = f2bf(f.x); u.y = f2bf(f.y); u.z = f2bf(f.z); u.w = f2bf(f.w);
    ((ushort4*)out)[i] = u;
}

// ------- K1/K4: C[m,n] = sum_k A[m,k]*W[n,k], bf16 MFMA (m97 structure) ----
__global__ __launch_bounds__(256) void gemm_nt_bf16(
    const ushort* __restrict__ A, const ushort* __restrict__ W,
    float* __restrict__ C, int M, int N, int K)
{
    __shared__ ushort As[128 * 32];
    __shared__ ushort Bs[128 * 32];
    const int t = threadIdx.x;
    const int wave = t >> 6, lane = t & 63;
    const int m0 = blockIdx.y * 128, n0 = blockIdx.x * 128;
    const int wm = (wave >> 1) * 64, wn = (wave & 1) * 64;
    const int lrow = lane & 15, lquad = lane >> 4;

    f32x4 acc[4][4];
#pragma unroll
    for (int i = 0; i < 4; ++i)
#pragma unroll
        for (int j = 0; j < 4; ++j) acc[i][j] = (f32x4){0.f, 0.f, 0.f, 0.f};

    for (int k0 = 0; k0 < K; k0 += 32) {
        __syncthreads();
#pragma unroll
        for (int i = 0; i < 2; ++i) {
            int chunk = t + 256 * i;
            int row = chunk >> 2, seg = chunk & 3;
            int ubase = (wave * 64 + 256 * i) * 8;
            __builtin_amdgcn_global_load_lds(
                (const gu32*)(A + (size_t)(m0 + row) * K + k0 + seg * 8),
                (lu32*)(As + ubase), 16, 0, 0);
            __builtin_amdgcn_global_load_lds(
                (const gu32*)(W + (size_t)(n0 + row) * K + k0 + seg * 8),
                (lu32*)(Bs + ubase), 16, 0, 0);
        }
        __syncthreads();

        bf16x8 af[4], bf[4];
#pragma unroll
        for (int i = 0; i < 4; ++i) {
            af[i] = *(const bf16x8*)(As + (wm + i * 16 + lrow) * 32 + lquad * 8);
            bf[i] = *(const bf16x8*)(Bs + (wn + i * 16 + lrow) * 32 + lquad * 8);
        }
#pragma unroll
        for (int i = 0; i < 4; ++i)
#pragma unroll
            for (int j = 0; j < 4; ++j)
                acc[i][j] = __builtin_amdgcn_mfma_f32_16x16x32_bf16(
                    af[i], bf[j], acc[i][j], 0, 0, 0);
    }
#pragma unroll
    for (int i = 0; i < 4; ++i)
#pragma unroll
        for (int j = 0; j < 4; ++j) {
            float* cp = C + (size_t)(m0 + wm + i * 16 + lquad * 4) * N
                          + n0 + wn + j * 16 + lrow;
#pragma unroll
            for (int r = 0; r < 4; ++r) cp[(size_t)r * N] = acc[i][j][r];
        }
}

// ------ K2: RMSNorm + RoPE + scale + bf16; V written CONTIGUOUS (b,kvh,s,d)
__global__ __launch_bounds__(128) void norm_rope(
    const float* __restrict__ qkv, const float* __restrict__ freqs,
    const float* __restrict__ qw, const float* __restrict__ kw,
    ushort* __restrict__ qo, ushort* __restrict__ ko, ushort* __restrict__ vo)
{
    const int bs = blockIdx.x;
    const int head = blockIdx.y;        // [0,16)=q, [16,20)=k, [20,24)=v
    const int d = threadIdx.x;
    const int b = bs >> 11, s = bs & (S_ - 1);
    const float x = qkv[(size_t)bs * EQKV_ + head * HD_ + d];

    if (head >= NH_ + NKV_) {           // V: bf16, contiguous (coalesced)
        const int vh = head - (NH_ + NKV_);
        vo[((size_t)(b * NKV_ + vh) * S_ + s) * HD_ + d] = f2bf(x);
        return;
    }
    __shared__ float wsum[2];
    float sq = x * x;
#pragma unroll
    for (int off = 1; off < 64; off <<= 1) sq += __shfl_xor(sq, off);
    if ((threadIdx.x & 63) == 0) wsum[threadIdx.x >> 6] = sq;
    __syncthreads();
    const float rs = rsqrtf((wsum[0] + wsum[1]) * (1.0f / HD_) + EPS_);
    const bool isq = head < NH_;
    const float w = isq ? qw[d] : kw[d];
    const float xn = x * rs * w;
    const float other = __shfl_xor(xn, 1);
    const float fr = freqs[s * HD_ + (d & ~1)];
    const float fi = freqs[s * HD_ + (d & ~1) + 1];
    float out = (d & 1) ? fmaf(xn, fr, other * fi)
                        : fmaf(xn, fr, -other * fi);
    if (isq) {
        out *= QSCALE_;
        qo[((size_t)(b * NH_ + head) * S_ + s) * HD_ + d] = f2bf(out);
    } else {
        const int kh = head - NH_;
        ko[((size_t)(b * NKV_ + kh) * S_ + s) * HD_ + d] = f2bf(out);
    }
}

// ---- transpose V: (bh, s, d) -> (bh, d, s), 64x64 LDS tiles, bf16 --------
// grid (S/64, HD/64, B*NKV), block 256
__global__ __launch_bounds__(256) void transpose_v(
    const ushort* __restrict__ in, ushort* __restrict__ out)
{
    __shared__ ushort Ts[64][68];
    const int t = threadIdx.x;
    const int s0 = blockIdx.x * 64, d0 = blockIdx.y * 64, bh = blockIdx.z;
    const ushort* ip = in + (size_t)bh * S_ * HD_;
    ushort* op = out + (size_t)bh * HD_ * S_;
    const int r = t >> 4, c4 = (t & 15) * 4;
#pragma unroll
    for (int p = 0; p < 4; ++p) {
        ushort4 u = *(const ushort4*)&ip[(size_t)(s0 + p * 16 + r) * HD_ + d0 + c4];
        Ts[p * 16 + r][c4] = u.x; Ts[p * 16 + r][c4 + 1] = u.y;
        Ts[p * 16 + r][c4 + 2] = u.z; Ts[p * 16 + r][c4 + 3] = u.w;
    }
    __syncthreads();
#pragma unroll
    for (int p = 0; p < 4; ++p) {
        ushort4 u;
        u.x = Ts[c4][p * 16 + r]; u.y = Ts[c4 + 1][p * 16 + r];
        u.z = Ts[c4 + 2][p * 16 + r]; u.w = Ts[c4 + 3][p * 16 + r];
        *(ushort4*)&op[(size_t)(d0 + p * 16 + r) * S_ + s0 + c4] = u;
    }
}

// ------------- K3: causal flash attention, bf16 MFMA, 2 q-slabs/wave ------
// grid (S/128, NH, B), block 256 = 4 waves; wave owns q rows [w*32, w*32+32)
__global__ __launch_bounds__(256, 3) void flash_attn_mfma(
    const ushort* __restrict__ Q,   // (B,NH,S,HD) bf16, pre-scaled
    const ushort* __restrict__ K,   // (B,NKV,S,HD) bf16
    const ushort* __restrict__ V,   // (B,NKV,HD,S) bf16 transposed
    ushort* __restrict__ Y)         // (B,S,NH*HD) bf16
{
    __shared__ ushort Ks[4 * 64 * 32];    // [kstep][krow][32]   16 KB
    __shared__ ushort Vs[2 * 128 * 32];   // [kkstep][d][32]     16 KB
    __shared__ ushort Ps[8 * 16 * 72];    // [wave*2+slab][16][72] 18 KB

    const int t = threadIdx.x, w = t >> 6, lane = t & 63;
    const int lx = lane & 15, quad = lane >> 4;
    const int h = blockIdx.y, b = blockIdx.z;
    const int qt = (int)gridDim.x - 1 - (int)blockIdx.x;  // heavy blocks first
    const int q0 = qt * 128;
    const int kvh = h >> 2;
    const int srow = lane >> 2, sseg = lane & 3;

    const ushort* qb = Q + ((size_t)(b * NH_ + h) * S_ + q0) * HD_;
    const ushort* kb = K + ((size_t)(b * NKV_ + kvh) * S_) * HD_;
    const ushort* vb = V + ((size_t)(b * NKV_ + kvh) * HD_) * S_;

    // Q A-fragments for both slabs, kept in registers
    bf16x8 aq[2][4];
#pragma unroll
    for (int sl = 0; sl < 2; ++sl)
#pragma unroll
        for (int ks = 0; ks < 4; ++ks)
            aq[sl][ks] = *(const bf16x8*)(qb + (size_t)(w * 32 + sl * 16 + lx) * HD_
                                          + ks * 32 + quad * 8);

    f32x4 o[2][8];
#pragma unroll
    for (int sl = 0; sl < 2; ++sl)
#pragma unroll
        for (int j = 0; j < 8; ++j) o[sl][j] = (f32x4){0.f, 0.f, 0.f, 0.f};
    float mrow[2][4], lrow[2][4];
#pragma unroll
    for (int sl = 0; sl < 2; ++sl)
#pragma unroll
        for (int r = 0; r < 4; ++r) { mrow[sl][r] = -INFINITY; lrow[sl][r] = 0.f; }

    const int ntiles = 2 * qt + 2;
    for (int tk = 0; tk < ntiles; ++tk) {
        const int k0 = tk * 64;
        __syncthreads();                 // all waves done reading prev Ks/Vs
#pragma unroll
        for (int i = 0; i < 4; ++i)      // stage K tile (lane-linear per wave)
            __builtin_amdgcn_global_load_lds(
                (const gu32*)(kb + (size_t)(k0 + w * 16 + srow) * HD_ + i * 32 + sseg * 8),
                (lu32*)(Ks + i * 2048 + w * 512), 16, 0, 0);
#pragma unroll
        for (int i = 0; i < 4; ++i) {    // stage V^T tile
            int kks = i >> 1, hf = i & 1;
            int dr = hf * 64 + w * 16 + srow;
            __builtin_amdgcn_global_load_lds(
                (const gu32*)(vb + (size_t)dr * S_ + k0 + kks * 32 + sseg * 8),
                (lu32*)(Vs + kks * 4096 + hf * 2048 + w * 512), 16, 0, 0);
        }
        __syncthreads();                 // staged data visible

        // ---- S = Q K^T : 2 slabs share each bk fragment ----
        f32x4 s[2][4];
#pragma unroll
        for (int sl = 0; sl < 2; ++sl)
#pragma unroll
            for (int j = 0; j < 4; ++j) s[sl][j] = (f32x4){0.f, 0.f, 0.f, 0.f};
#pragma unroll
        for (int ks = 0; ks < 4; ++ks)
#pragma unroll
            for (int j = 0; j < 4; ++j) {
                bf16x8 bk = *(const bf16x8*)(Ks + ks * 2048 + (j * 16 + lx) * 32 + quad * 8);
                s[0][j] = __builtin_amdgcn_mfma_f32_16x16x32_bf16(aq[0][ks], bk, s[0][j], 0, 0, 0);
                s[1][j] = __builtin_amdgcn_mfma_f32_16x16x32_bf16(aq[1][ks], bk, s[1][j], 0, 0, 0);
            }

        // ---- causal mask + online softmax, per slab ----
#pragma unroll
        for (int sl = 0; sl < 2; ++sl) {
            const int qrb = q0 + w * 32 + sl * 16 + quad * 4;
#pragma unroll
            for (int reg = 0; reg < 4; ++reg) {
                const int qrow = qrb + reg;
#pragma unroll
                for (int j = 0; j < 4; ++j)
                    if (k0 + lx + 16 * j > qrow) s[sl][j][reg] = -INFINITY;
                float rm = fmaxf(fmaxf(s[sl][0][reg], s[sl][1][reg]),
                                 fmaxf(s[sl][2][reg], s[sl][3][reg]));
#pragma unroll
                for (int off = 1; off < 16; off <<= 1) rm = fmaxf(rm, __shfl_xor(rm, off));
                const float mn = fmaxf(mrow[sl][reg], rm);
                const float alpha = __expf(mrow[sl][reg] - mn);
                float rsum = 0.f;
                float p[4];
#pragma unroll
                for (int j = 0; j < 4; ++j) {
                    p[j] = __expf(s[sl][j][reg] - mn);
                    rsum += p[j];
                }
#pragma unroll
                for (int off = 1; off < 16; off <<= 1) rsum += __shfl_xor(rsum, off);
                lrow[sl][reg] = lrow[sl][reg] * alpha + rsum;
                mrow[sl][reg] = mn;
#pragma unroll
                for (int j = 0; j < 8; ++j) o[sl][j][reg] *= alpha;
#pragma unroll
                for (int j = 0; j < 4; ++j)
                    Ps[(w * 2 + sl) * 1152 + (quad * 4 + reg) * 72 + lx + 16 * j] = f2bf(p[j]);
            }
        }
        // ---- O += P V : 2 slabs share each bv fragment ----
        bf16x8 ap[2][2];
#pragma unroll
        for (int sl = 0; sl < 2; ++sl)
#pragma unroll
            for (int ks2 = 0; ks2 < 2; ++ks2)
                ap[sl][ks2] = *(const bf16x8*)(Ps + (w * 2 + sl) * 1152 + lx * 72
                                               + ks2 * 32 + quad * 8);
#pragma unroll
        for (int jd = 0; jd < 8; ++jd)
#pragma unroll
            for (int ks2 = 0; ks2 < 2; ++ks2) {
                bf16x8 bv = *(const bf16x8*)(Vs + ks2 * 4096 + (jd * 16 + lx) * 32 + quad * 8);
                o[0][jd] = __builtin_amdgcn_mfma_f32_16x16x32_bf16(ap[0][ks2], bv, o[0][jd], 0, 0, 0);
                o[1][jd] = __builtin_amdgcn_mfma_f32_16x16x32_bf16(ap[1][ks2], bv, o[1][jd], 0, 0, 0);
            }
    }
    // ---- epilogue ----
#pragma unroll
    for (int sl = 0; sl < 2; ++sl)
#pragma unroll
        for (int reg = 0; reg < 4; ++reg) {
            const float inv = 1.0f / lrow[sl][reg];
            const size_t yb = (size_t)(b * S_ + q0 + w * 32 + sl * 16 + quad * 4 + reg)
                              * (NH_ * HD_) + h * HD_ + lx;
#pragma unroll
            for (int jd = 0; jd < 8; ++jd)
                Y[yb + jd * 16] = f2bf(o[sl][jd][reg] * inv);
        }
}

extern "C" void kernel_launch(void* const* d_in, const int* in_sizes, int n_in,
                              void* d_out, int out_size, void* d_ws, size_t ws_size,
                              hipStream_t stream)
{
    const float* x     = (const float*)d_in[0];
    const float* freqs = (const float*)d_in[1];
    const float* wqkv  = (const float*)d_in[2];
    const float* wo    = (const float*)d_in[3];
    const float* qw    = (const float*)d_in[4];
    const float* kw    = (const float*)d_in[5];
    float* out = (float*)d_out;

    // ws layout (100,663,296 B, byte offsets; liveness-checked):
    //   [0..50.33M)       qkv fp32 (K1 out -> norm_rope in);
    //                     then wobf@0 (8.39M) + ybf@8.39M (16.78M)
    //   [50.33M..62.91M)  wqkvbf (K1 in); then qbf@50.33M (16.78M)
    //   [67.11M..71.30M)  kbf
    //   [71.30M..75.50M)  vtb  (V^T, flash input)
    //   [75.50M..83.89M)  vtmp (contiguous V, transpose_v input)
    //   [83.89M..100.66M) xbf (K1 in only)
    char* ws = (char*)d_ws;
    float*  qkv    = (float*)ws;
    ushort* wqkvbf = (ushort*)(ws + 50331648);
    ushort* xbf    = (ushort*)(ws + 83886080);
    ushort* qbf    = (ushort*)(ws + 50331648);
    ushort* kbf    = (ushort*)(ws + 67108864);
    ushort* vtb    = (ushort*)(ws + 71303168);
    ushort* vtmp   = (ushort*)(ws + 75497472);
    ushort* wobf   = (ushort*)(ws + 0);
    ushort* ybf    = (ushort*)(ws + 8388608);

    pack_bf16<<<(M_ * D_ / 4 + 255) / 256, 256, 0, stream>>>(x, xbf, M_ * D_ / 4);
    pack_bf16<<<(EQKV_ * D_ / 4 + 255) / 256, 256, 0, stream>>>(wqkv, wqkvbf,
                                                                EQKV_ * D_ / 4);
    // K1: qkv = x @ wqkv^T  (bf16 MFMA, fp32 out)
    gemm_nt_bf16<<<dim3(EQKV_ / 128, M_ / 128), 256, 0, stream>>>(
        xbf, wqkvbf, qkv, M_, EQKV_, D_);
    // K2: rmsnorm + rope -> bf16 q/k + contiguous bf16 V
    norm_rope<<<dim3(M_, NH_ + 2 * NKV_), 128, 0, stream>>>(qkv, freqs, qw, kw,
                                                            qbf, kbf, vtmp);
    // V transpose (coalesced both sides)
    transpose_v<<<dim3(S_ / 64, HD_ / 64, B_ * NKV_), 256, 0, stream>>>(vtmp, vtb);
    // pack wo into dead qkv region
    pack_bf16<<<(D_ * NH_ * HD_ / 4 + 255) / 256, 256, 0, stream>>>(
        wo, wobf, D_ * NH_ * HD_ / 4);
    // K3: MFMA flash attention -> ybf
    flash_attn_mfma<<<dim3(S_ / 128, NH_, B_), 256, 0, stream>>>(qbf, kbf, vtb, ybf);
    // K4: out = y @ wo^T  (bf16 MFMA)
    gemm_nt_bf16<<<dim3(D_ / 128, M_ / 128), 256, 0, stream>>>(
        ybf, wobf, out, M_, D_, NH_ * HD_);
}